// Round 7
// baseline (305.147 us; speedup 1.0000x reference)
//
#include <hip/hip_runtime.h>
#include <stdint.h>

#define M_DIM 32768
#define K_DIM 1024
#define N_DIM 1024

typedef int v4i __attribute__((ext_vector_type(4)));

// ---- fragment-packed tiled layout (shared by xq and wt) ----
// addr(m,k) = (m>>4)*16384 + (k>>6)*1024 + ((k>>4)&3)*256 + (m&15)*16 + (k&15)
// => for a 16-row panel p and K-step kt, lane l's MFMA fragment (row=l&15,
//    kquad=l>>4) is the 16 B at p*16384 + kt*1024 + l*16: wave-contiguous 1 KB.

// ---------------- kernel 1: fused minmax partials + w transpose+pack ----------------
// blocks 0..1023   : per-block min/max partials over x (32 float4 iters/thread)
// blocks 1024..2047: transpose w [K,N] int32 -> packed wt (int8, tiled layout)
__global__ void k_prep(const float* __restrict__ x,
                       float* __restrict__ pmin, float* __restrict__ pmax,
                       const int* __restrict__ w, int8_t* __restrict__ wt) {
    int t = threadIdx.x;
    if (blockIdx.x < 1024) {
        long gid = (long)blockIdx.x * 256 + t;
        const float4* x4 = (const float4*)x;
        const long n4 = (long)M_DIM * K_DIM / 4;  // 8M, exactly 32 iters/thread
        float mn = INFINITY, mx = -INFINITY;
#pragma unroll 4
        for (long i = gid; i < n4; i += 1024 * 256) {
            float4 v = x4[i];
            mn = fminf(mn, fminf(fminf(v.x, v.y), fminf(v.z, v.w)));
            mx = fmaxf(mx, fmaxf(fmaxf(v.x, v.y), fmaxf(v.z, v.w)));
        }
        __shared__ float smn[256], smx[256];
        smn[t] = mn; smx[t] = mx;
        __syncthreads();
        for (int s = 128; s > 0; s >>= 1) {
            if (t < s) {
                smn[t] = fminf(smn[t], smn[t + s]);
                smx[t] = fmaxf(smx[t], smx[t + s]);
            }
            __syncthreads();
        }
        if (t == 0) { pmin[blockIdx.x] = smn[0]; pmax[blockIdx.x] = smx[0]; }
    } else {
        __shared__ int8_t tile[32][33];
        int b = blockIdx.x - 1024;          // 0..1023
        int bn = (b & 31) * 32;             // N tile
        int bk = (b >> 5) * 32;             // K tile
        int tx = t & 31, ty = t >> 5;       // 32x8
#pragma unroll
        for (int i = 0; i < 32; i += 8)
            tile[ty + i][tx] = (int8_t)w[(long)(bk + ty + i) * N_DIM + bn + tx];
        __syncthreads();
#pragma unroll
        for (int i = 0; i < 32; i += 8) {
            int n = bn + ty + i;
            int k = bk + tx;
            long addr = (long)(n >> 4) * 16384 + (k >> 6) * 1024 +
                        ((k >> 4) & 3) * 256 + (n & 15) * 16 + (k & 15);
            wt[addr] = tile[tx][ty + i];
        }
    }
}

// ---------------- quantize helper (IEEE div + rintf = RTNE, matches jnp) ----------------
__device__ __forceinline__ unsigned q4(float4 v, float s, float zp) {
    int a = (int)fminf(fmaxf(rintf(v.x / s) + zp, -128.0f), 127.0f);
    int b = (int)fminf(fmaxf(rintf(v.y / s) + zp, -128.0f), 127.0f);
    int c = (int)fminf(fmaxf(rintf(v.z / s) + zp, -128.0f), 127.0f);
    int d = (int)fminf(fmaxf(rintf(v.w / s) + zp, -128.0f), 127.0f);
    return (a & 255) | ((b & 255) << 8) | ((c & 255) << 16) | ((d & 255) << 24);
}

// ---------------- kernel 2: finalize + quantize + REPACK x -> tiled int8 ----------------
// 2048 blocks x 256 threads; block b owns panel b (rows [b*16, b*16+16), all K).
// P0: re-reduce the 2x1024 min/max partials -> (s, zp) (order-independent min/max
//     -> identical in every block). Block 0 publishes sp for k_gemm's epilogue.
// P1: read 64 KB x-panel fully coalesced (float4), quantize once, store to LDS
//     row-major [16][1024+16B pad].
// P2: read 16 B k-chunks from LDS, store uint4 to packed xq: thread t, rep v:
//     chunk c = v*256+t -> (r=c&15, q=(c>>4)&3, kt=c>>6), out addr = c*16 in panel
//     -> both LDS reads (16B-aligned, banks uniformly spread) and global stores
//     (wave-contiguous 1 KB) are conflict-free/coalesced.
__global__ void k_quant(const float* __restrict__ x,
                        const float* __restrict__ pmin,
                        const float* __restrict__ pmax,
                        float* __restrict__ sp,
                        int8_t* __restrict__ xq) {
    __shared__ unsigned lq[16 * 260];   // 16 rows x 1040 B (16B pad keeps alignment)
    __shared__ float red[2][256];

    const int t = threadIdx.x;

    // ---- P0 ----
    float mn = INFINITY, mx = -INFINITY;
#pragma unroll
    for (int i = 0; i < 4; i++) {
        mn = fminf(mn, pmin[i * 256 + t]);
        mx = fmaxf(mx, pmax[i * 256 + t]);
    }
    red[0][t] = mn; red[1][t] = mx;
    __syncthreads();
    for (int ss = 128; ss > 0; ss >>= 1) {
        if (t < ss) {
            red[0][t] = fminf(red[0][t], red[0][t + ss]);
            red[1][t] = fmaxf(red[1][t], red[1][t + ss]);
        }
        __syncthreads();
    }
    const float min_neg = fminf(red[0][0], 0.0f);
    const float max_pos = fmaxf(red[1][0], 0.0f);
    float s = (max_pos - min_neg) / 255.0f;          // IEEE div, matches jnp
    s = fmaxf(s, 1.1920928955078125e-07f);           // np.finfo(f32).eps
    float zp = -128.0f - rintf(min_neg / s);         // rintf = RTNE = jnp.round
    zp = fminf(fmaxf(zp, -128.0f), 127.0f);
    if (blockIdx.x == 0 && t == 0) { sp[0] = s; sp[1] = zp; }

    // ---- P1: quantize panel into LDS (row-major, padded) ----
    const float4* xp = (const float4*)x + (long)blockIdx.x * 4096;
#pragma unroll
    for (int v = 0; v < 16; v++) {
        int i = v * 256 + t;             // 0..4095; row = i>>8, kword = i&255
        float4 val = xp[i];
        lq[(i >> 8) * 260 + (i & 255)] = q4(val, s, zp);
    }
    __syncthreads();

    // ---- P2: emit packed tiles ----
    uint4* outp = (uint4*)(xq + (long)blockIdx.x * 16384);
#pragma unroll
    for (int v = 0; v < 4; v++) {
        int c = v * 256 + t;             // chunk 0..1023
        int r = c & 15, q = (c >> 4) & 3, kt = c >> 6;
        const uint4 val = *(const uint4*)&lq[r * 260 + kt * 16 + q * 4];
        outp[c] = val;                   // wave-contiguous 16 B/lane store
    }
}

// ---------------- kernel 3: ZERO-LDS int8 GEMM + dequant + bias ----------------
// 128x128 tile per block (4 waves, each 64x64 via 4x4 MFMA 16x16x64 tiles), BK=64.
// Both operands are fragment-packed: each wave's A/B fragment load is ONE
// wave-contiguous global_load_dwordx4 (1 KB/instr) straight into VGPRs.
// Register double-buffer across K-steps; NO LDS, NO barriers, NO lock-step:
// 12 waves/CU free-run, MFMA/L2 latency mutually hidden by TLP + prefetch.
// XCD-bijective block swizzle keeps the 8 N-blocks of an A panel on one XCD.
__global__ __launch_bounds__(256, 3) void k_gemm(
    const int8_t* __restrict__ xq, const int8_t* __restrict__ wt,
    const float* __restrict__ sp, const float* __restrict__ w_scales,
    const int* __restrict__ wsums, const float* __restrict__ bias,
    float* __restrict__ out) {
    const int t = threadIdx.x;
    const int orig = blockIdx.x;
    const int swz = (orig & 7) * 256 + (orig >> 3);  // nwg=2048, %8==0 -> bijective
    const int m0 = (swz >> 3) * 128;   // 0..255 -> M tile
    const int n0 = (swz & 7) * 128;    // 0..7   -> N tile
    const int w = t >> 6, l = t & 63, quad = l >> 4, r = l & 15;
    const int m0w = m0 + (w & 1) * 64;
    const int n0w = n0 + (w >> 1) * 64;

    // packed: panel stride 16384 B, K-step stride 1024 B, lane chunk l*16
    const int8_t* pa = xq + (long)m0w * 1024 + l * 16;
    const int8_t* pb = wt + (long)n0w * 1024 + l * 16;

    v4i acc[4][4];
#pragma unroll
    for (int i = 0; i < 4; i++)
#pragma unroll
        for (int j = 0; j < 4; j++) acc[i][j] = (v4i){0, 0, 0, 0};

    v4i af[2][4], bf[2][4];
#pragma unroll
    for (int i = 0; i < 4; i++) af[0][i] = *(const v4i*)(pa + i * 16384);
#pragma unroll
    for (int j = 0; j < 4; j++) bf[0][j] = *(const v4i*)(pb + j * 16384);

#pragma unroll
    for (int kt = 0; kt < 16; ++kt) {
        const int cur = kt & 1, nxt = cur ^ 1;
        if (kt < 15) {
#pragma unroll
            for (int i = 0; i < 4; i++)
                af[nxt][i] = *(const v4i*)(pa + i * 16384 + (kt + 1) * 1024);
#pragma unroll
            for (int j = 0; j < 4; j++)
                bf[nxt][j] = *(const v4i*)(pb + j * 16384 + (kt + 1) * 1024);
        }
        __builtin_amdgcn_s_setprio(1);
#pragma unroll
        for (int i = 0; i < 4; i++)
#pragma unroll
            for (int j = 0; j < 4; j++)
                acc[i][j] = __builtin_amdgcn_mfma_i32_16x16x64_i8(
                    af[cur][i], bf[cur][j], acc[i][j], 0, 0, 0);
        __builtin_amdgcn_s_setprio(0);
    }

    // epilogue: y = x_scale * w_scales[n] * (acc - x_zp * wsum[n]) + bias[n]
    const float scale = sp[0], zp = sp[1];
#pragma unroll
    for (int j = 0; j < 4; j++) {
        int n = n0w + j * 16 + r;
        float sj = scale * w_scales[n];
        float cj = zp * (float)wsums[n];
        float bj = bias[n];
#pragma unroll
        for (int i = 0; i < 4; i++) {
            int mbase = m0w + i * 16 + quad * 4;
#pragma unroll
            for (int e = 0; e < 4; e++) {
                out[(long)(mbase + e) * N_DIM + n] = sj * ((float)acc[i][j][e] - cj) + bj;
            }
        }
    }
}

// ---------------- launcher ----------------
extern "C" void kernel_launch(void* const* d_in, const int* in_sizes, int n_in,
                              void* d_out, int out_size, void* d_ws, size_t ws_size,
                              hipStream_t stream) {
    const float* x        = (const float*)d_in[0];
    const int*   w_int8_t = (const int*)d_in[1];   // int8 values widened to int32 by harness
    const float* w_scales = (const float*)d_in[2];
    const int*   w_sums   = (const int*)d_in[3];
    const float* bias     = (const float*)d_in[4];
    float* out = (float*)d_out;

    // ws layout: [0..1023] pmin, [1024..2047] pmax, [2048..2049] (scale,zp),
    // byte 16384: wt packed (1 MB), byte 16384+1MB: xq packed (32 MB)
    float* wsf  = (float*)d_ws;
    float* pmin = wsf;
    float* pmax = wsf + 1024;
    float* sp   = wsf + 2048;
    int8_t* wt  = (int8_t*)d_ws + 16384;
    int8_t* xq  = (int8_t*)d_ws + 16384 + (size_t)K_DIM * N_DIM;

    k_prep<<<2048, 256, 0, stream>>>(x, pmin, pmax, w_int8_t, wt);
    k_quant<<<2048, 256, 0, stream>>>(x, pmin, pmax, sp, xq);
    k_gemm<<<2048, 256, 0, stream>>>(xq, wt, sp, w_scales, w_sums, bias, out);
}